// Round 1
// 62.847 us; speedup vs baseline: 1.0097x; 1.0097x over previous
//
#include <hip/hip_runtime.h>

// KaolinRenderer: coverage-mask rasterizer.
// Output = repeat(mask[B,H,W], 3) — the reference z-buffer is dead code.
//
// BIT-EXACTNESS IS CRITICAL: mask is binary, threshold 2e-2. Faces with
// w-clamped vertices (|ndc| ~1e8) have catastrophically-cancelling edge
// functions whose sign is rounding-determined. We mirror the numpy reference's
// float32 op order exactly and disable FMA contraction. Skipping faces once
// `covered` is true is safe (sticky OR); changing per-face arithmetic is not.
//
// R7 (this round): two changes to the raster inner loop.
//  (1) Survivor broadcast via v_readlane instead of __shfl. The broadcast
//      lane k comes from __ballot and is wave-uniform, but the compiler
//      can't prove it through __ffsll, so __shfl lowered to 6 ds_bpermute
//      per survivor (LDS pipe, ~30cy + lgkmcnt waits, unhidden at 2
//      waves/SIMD). Explicit __builtin_amdgcn_readlane moves the 12 values
//      (6 coords + 6 diffs) through the scalar file with no LDS traffic.
//      Broadcasting the diffs too avoids SGPR-SGPR float subs (no scalar
//      FP on CDNA). Bit-exact: readlane returns lane k's exact bits; lane k
//      computed each diff with the same f32 inputs+op as the reference.
//  (2) Wave footprint 16x4 -> 8x8. The half-plane cull acceptance scales
//      with rect width+height (0.15625 -> 0.125 NDC) => ~15-20% fewer
//      survivors. CULL_EPS bound is rect-independent (|px|,|py| <= 1).
// R6: face_pack writes only 6 NDC coords/face; per-lane register cull +
// ballot compaction (R4-validated err bound); no memory ops in inner loop.

#pragma clang fp contract(off)

#define HW      256
#define BATCH   2
#define VCOUNT  4096
#define FCOUNT  4096
#define CULL_EPS 1.52587890625e-05f   // 2^-16

__global__ __launch_bounds__(256)
void face_pack_kernel(const float* __restrict__ verts,
                      const int* __restrict__ faces,
                      const float* __restrict__ R,
                      const float* __restrict__ T,
                      float4* __restrict__ fxy4,   // [B*F] (x0,y0,x1,y1)
                      float2* __restrict__ fxy2)   // [B*F] (x2,y2)
{
#pragma clang fp contract(off)
    int gid = blockIdx.x * blockDim.x + threadIdx.x;
    if (gid >= BATCH * FCOUNT) return;
    int b = gid / FCOUNT;

    const float fproj = 1.7320508075688772f;   // 1/tan(30deg), f64->f32 like numpy

    const float* Rb = R + b * 9;
    const float* Tb = T + b * 3;

    // t_i = -((Rt[i][0]*T0 + Rt[i][1]*T1) + Rt[i][2]*T2), Rt[i][j] = R[j][i]
    float t0 = -((Rb[0*3+0]*Tb[0] + Rb[1*3+0]*Tb[1]) + Rb[2*3+0]*Tb[2]);
    float t1 = -((Rb[0*3+1]*Tb[0] + Rb[1*3+1]*Tb[1]) + Rb[2*3+1]*Tb[2]);
    float t2 = -((Rb[0*3+2]*Tb[0] + Rb[1*3+2]*Tb[1]) + Rb[2*3+2]*Tb[2]);

    // VP rows 0 (x), 1 (y), 3 (w) only.
    float VP00 = fproj * Rb[0*3+0], VP01 = fproj * Rb[1*3+0],
          VP02 = fproj * Rb[2*3+0], VP03 = fproj * t0;
    float VP10 = fproj * Rb[0*3+1], VP11 = fproj * Rb[1*3+1],
          VP12 = fproj * Rb[2*3+1], VP13 = fproj * t1;
    float VP30 = -Rb[0*3+2], VP31 = -Rb[1*3+2],
          VP32 = -Rb[2*3+2], VP33 = -t2;

    const int* fp = faces + (size_t)gid * 3;
    float xs[3], ys[3];
#pragma unroll
    for (int j = 0; j < 3; ++j) {
        const float* vv = verts + ((size_t)b * VCOUNT + fp[j]) * 3;
        float vx = vv[0], vy = vv[1], vz = vv[2];
        // Identical op sequence to the reference einsum (sequential adds),
        // contract off => bit-identical NDC for every reference to a vertex.
        float cx = ((vx*VP00 + vy*VP01) + vz*VP02) + VP03;
        float cy = ((vx*VP10 + vy*VP11) + vz*VP12) + VP13;
        float cw = ((vx*VP30 + vy*VP31) + vz*VP32) + VP33;
        float w = fmaxf(cw, 1e-8f);
        xs[j] = cx / w;
        ys[j] = cy / w;
    }

    fxy4[gid] = make_float4(xs[0], ys[0], xs[1], ys[1]);
    fxy2[gid] = make_float2(xs[2], ys[2]);
}

// Wave-uniform broadcast through the scalar file (v_readlane_b32).
__device__ __forceinline__ float bcast_lane(float v, int k) {
    return __int_as_float(__builtin_amdgcn_readlane(__float_as_int(v), k));
}

__global__ __launch_bounds__(256)
void raster_kernel(const float4* __restrict__ fxy4,
                   const float2* __restrict__ fxy2,
                   float* __restrict__ out)
{
#pragma clang fp contract(off)
    int b    = blockIdx.y;
    int tile = blockIdx.x;                       // 16x16 tiles over 256x256
    int tx = (tile & 15) << 4;
    int ty = (tile >> 4) << 4;

    // 8x8 quadrant per wave (tighter cull rect than 16x4).
    int wave = threadIdx.x >> 6;
    int lane = threadIdx.x & 63;
    int qx = tx + ((wave & 1) << 3);
    int qy = ty + ((wave >> 1) << 3);
    int px_i = qx + (lane & 7);
    int py_i = qy + (lane >> 3);

    // Same formula as reference: ((i + 0.5)/W)*2 - 1
    float px = (((float)px_i + 0.5f) / 256.0f) * 2.0f - 1.0f;
    float py = (((float)py_i + 0.5f) / 256.0f) * 2.0f - 1.0f;

    // This wave's 8x8 rect (pixel formula is monotone in index).
    float pxlo = (((float)qx       + 0.5f) / 256.0f) * 2.0f - 1.0f;
    float pxhi = (((float)(qx + 7) + 0.5f) / 256.0f) * 2.0f - 1.0f;
    float pylo = (((float)qy       + 0.5f) / 256.0f) * 2.0f - 1.0f;
    float pyhi = (((float)(qy + 7) + 0.5f) / 256.0f) * 2.0f - 1.0f;

    const float4* f4 = fxy4 + (size_t)b * FCOUNT;
    const float2* f2 = fxy2 + (size_t)b * FCOUNT;

    bool covered = false;

    for (int g = 0; g < FCOUNT; g += 64) {
        if (__all((int)covered)) break;

        // Phase 1: lane owns face g+lane; coalesced 24B load, all-register cull.
        float4 q0 = f4[g + lane];
        float2 q1 = f2[g + lane];
        float x0 = q0.x, y0 = q0.y, x1 = q0.z, y1 = q0.w;
        float x2 = q1.x, y2 = q1.y;
        // Diffs: same ops as the reference's broadcast (x1-x0) etc.
        float d01x = x1 - x0, d01y = y1 - y0;
        float d12x = x2 - x1, d12y = y2 - y1;
        float d20x = x0 - x2, d20y = y0 - y2;

        // Conservative cull: e(p) ~= A*py + B*px + C over the wave rect.
        // Skippable iff some edge certifies e<0 everywhere AND some edge
        // certifies e>0 everywhere (kills both sign branches of `inside`).
        bool killneg = false, killpos = false;
        {
            float A[3]  = { d01x, d12x, d20x };
            float Bc[3] = { -d01y, -d12y, -d20y };
            float xa[3] = { x0, x1, x2 };
            float ya[3] = { y0, y1, y2 };
#pragma unroll
            for (int e = 0; e < 3; ++e) {
                float C = (-Bc[e]) * xa[e] - A[e] * ya[e];
                float err = CULL_EPS * (fabsf(A[e])  * (1.0f + fabsf(ya[e]))
                                      + fabsf(Bc[e]) * (1.0f + fabsf(xa[e])));
                float yh = (A[e]  > 0.0f) ? pyhi : pylo;
                float yl = (A[e]  > 0.0f) ? pylo : pyhi;
                float xh = (Bc[e] > 0.0f) ? pxhi : pxlo;
                float xl = (Bc[e] > 0.0f) ? pxlo : pxhi;
                float hi = A[e] * yh + Bc[e] * xh + C;
                float lo = A[e] * yl + Bc[e] * xl + C;
                killneg = killneg || (hi < -err);
                killpos = killpos || (lo >  err);
            }
        }
        bool skip = killneg && killpos;

        // Phase 2: survivors broadcast from the holding lane via v_readlane
        // (k is wave-uniform) — no LDS-pipe ops, no memory ops.
        unsigned long long m = __ballot((int)!skip);
        while (m) {
            if (__all((int)covered)) break;
            int k = __ffsll((long long)m) - 1;
            m &= m - 1;
            float bx0 = bcast_lane(x0, k), by0 = bcast_lane(y0, k);
            float bx1 = bcast_lane(x1, k), by1 = bcast_lane(y1, k);
            float bx2 = bcast_lane(x2, k), by2 = bcast_lane(y2, k);
            // Broadcast lane-k's diffs directly: identical f32 values to the
            // reference's (x1-x0) etc. (same inputs, same op, computed lane k).
            float bd01x = bcast_lane(d01x, k), bd01y = bcast_lane(d01y, k);
            float bd12x = bcast_lane(d12x, k), bd12y = bcast_lane(d12y, k);
            float bd20x = bcast_lane(d20x, k), bd20y = bcast_lane(d20y, k);
            // e = (x1-x0)*(py-y0) - (y1-y0)*(px-x0): mul, mul, sub — no FMA
            float e0 = bd01x * (py - by0) - bd01y * (px - bx0);
            float e1 = bd12x * (py - by1) - bd12y * (px - bx1);
            float e2 = bd20x * (py - by2) - bd20y * (px - bx2);
            float mn = fminf(fminf(e0, e1), e2);
            float mx = fmaxf(fmaxf(e0, e1), e2);
            covered = covered || (mn >= 0.0f) || (mx <= 0.0f);
        }
    }

    float val = covered ? 1.0f : 0.0f;
    size_t o = ((size_t)(b * HW + py_i) * HW + px_i) * 3;
    out[o + 0] = val;
    out[o + 1] = val;
    out[o + 2] = val;
}

extern "C" void kernel_launch(void* const* d_in, const int* in_sizes, int n_in,
                              void* d_out, int out_size, void* d_ws, size_t ws_size,
                              hipStream_t stream) {
    const float* verts = (const float*)d_in[0];   // [2,4096,3] f32
    const int*   faces = (const int*)d_in[1];     // [2,4096,3] i32
    const float* R     = (const float*)d_in[2];   // [2,3,3]    f32
    const float* T     = (const float*)d_in[3];   // [2,3]      f32
    float*       out   = (float*)d_out;           // [2,256,256,3] f32

    float4* fxy4 = (float4*)d_ws;                        // 128 KiB
    float2* fxy2 = (float2*)(fxy4 + BATCH * FCOUNT);     // 64 KiB

    int nf = BATCH * FCOUNT;
    face_pack_kernel<<<(nf + 255) / 256, 256, 0, stream>>>(verts, faces, R, T,
                                                           fxy4, fxy2);

    dim3 grid(256, BATCH);
    raster_kernel<<<grid, 256, 0, stream>>>(fxy4, fxy2, out);
}